// Round 8
// baseline (1165.821 us; speedup 1.0000x reference)
//
#include <hip/hip_runtime.h>
#include <cstdint>

#define BB 32
#define HH 4096
#define FF 4096
#define EE 8
#define NSLOT 16   // 8 experts x 2 slots of <=16 tokens
#define TSEG 16

// ---------------------------------------------------------------- gate ----
__global__ __launch_bounds__(256) void gate_kernel(const float* __restrict__ x,
                                                   const float* __restrict__ Wg,
                                                   float* __restrict__ logits) {
  int b = blockIdx.x;
  int tid = threadIdx.x;
  float acc[EE];
#pragma unroll
  for (int e = 0; e < EE; ++e) acc[e] = 0.f;
  const float* xb = x + (size_t)b * HH;
  for (int h = tid; h < HH; h += 256) {
    float xv = xb[h];
    const float4* wg = (const float4*)(Wg + (size_t)h * EE);
    float4 w0 = wg[0], w1 = wg[1];
    acc[0] = fmaf(xv, w0.x, acc[0]);
    acc[1] = fmaf(xv, w0.y, acc[1]);
    acc[2] = fmaf(xv, w0.z, acc[2]);
    acc[3] = fmaf(xv, w0.w, acc[3]);
    acc[4] = fmaf(xv, w1.x, acc[4]);
    acc[5] = fmaf(xv, w1.y, acc[5]);
    acc[6] = fmaf(xv, w1.z, acc[6]);
    acc[7] = fmaf(xv, w1.w, acc[7]);
  }
#pragma unroll
  for (int off = 32; off > 0; off >>= 1) {
#pragma unroll
    for (int e = 0; e < EE; ++e) acc[e] += __shfl_down(acc[e], off, 64);
  }
  __shared__ float part[4][EE];
  if ((tid & 63) == 0) {
#pragma unroll
    for (int e = 0; e < EE; ++e) part[tid >> 6][e] = acc[e];
  }
  __syncthreads();
  if (tid < EE) {
    logits[(size_t)b * EE + tid] =
        part[0][tid] + part[1][tid] + part[2][tid] + part[3][tid];
  }
}

// --------------------------------------------------------------- route ----
__global__ void route_kernel(const float* __restrict__ logits,
                             int* __restrict__ cnt,
                             int* __restrict__ tok,
                             float* __restrict__ wts,
                             int* __restrict__ ord) {
  if (threadIdx.x != 0 || blockIdx.x != 0) return;
  int e0[BB], e1[BB];
  float p0[BB], p1[BB];
  for (int b = 0; b < BB; ++b) {
    const float* L = logits + (size_t)b * EE;
    int i0 = 0;
    float v0 = L[0];
    for (int e = 1; e < EE; ++e) {
      float v = L[e];
      if (v > v0) { v0 = v; i0 = e; }
    }
    int i1 = (i0 == 0) ? 1 : 0;
    float v1 = L[i1];
    for (int e = 0; e < EE; ++e) {
      if (e == i0) continue;
      float v = L[e];
      if (v > v1) { v1 = v; i1 = e; }
    }
    float p = 1.f / (1.f + __expf(v1 - v0));
    e0[b] = i0; e1[b] = i1; p0[b] = p; p1[b] = 1.f - p;
  }
  for (int s = 0; s < NSLOT; ++s) {
    cnt[s] = 0;
    for (int t = 0; t < TSEG; ++t) { tok[s * TSEG + t] = 0; wts[s * TSEG + t] = 0.f; }
  }
  for (int e = 0; e < EE; ++e) {
    int c = 0;
    for (int b = 0; b < BB; ++b) {
      float w = 0.f;
      int sel = 0;
      if (e0[b] == e) { w = p0[b]; sel = 1; }
      else if (e1[b] == e) { w = p1[b]; sel = 1; }
      if (sel) {
        int s = e * 2 + (c >> 4);
        int t = c & 15;
        tok[s * TSEG + t] = b;
        wts[s * TSEG + t] = w;
        cnt[s] = t + 1;
        ++c;
      }
    }
  }
  int na = 0;
  for (int s = 0; s < NSLOT; ++s) if (cnt[s] > 0) ord[na++] = s;
  for (int s = 0; s < NSLOT; ++s) if (cnt[s] == 0) ord[na++] = s;
}

// -------------------------------------------------------------- buildx ----
__global__ __launch_bounds__(256) void buildx_kernel(const float* __restrict__ x,
                                                     const int* __restrict__ cnt,
                                                     const int* __restrict__ tok,
                                                     float* __restrict__ xseg) {
  int s = blockIdx.y;
  int c = cnt[s];
  if (c == 0) return;
  int tid = threadIdx.x;
  int t = tid & 15;
  int hoff = tid >> 4;
  int tk = tok[s * TSEG + t];
  bool act = t < c;
  int hbase = blockIdx.x * 256;
#pragma unroll
  for (int i = 0; i < 16; ++i) {
    int h = hbase + i * 16 + hoff;
    float v = act ? x[(size_t)tk * HH + h] : 0.f;
    xseg[((size_t)s * HH + h) * TSEG + t] = v;
  }
}

// --------------------------------------------------------------- passB ----
// Barrier-free streaming. Wave = (token-half, 64 cols); lane = 1 column.
// Weight: dword/lane (256 B/wave unique, coalesced), depth-16 register ring.
// x: wave-uniform broadcast 2x float4 per row from L2/L3, depth-4 ring.
// 8 FMA/row/lane. No LDS, no reduce: token-half waves write disjoint
// halves of h[col][16] directly.
__global__ __launch_bounds__(256) void passB8_kernel(const float* __restrict__ W1,
                                                     const float* __restrict__ W3,
                                                     const float* __restrict__ xseg,
                                                     float* __restrict__ h1seg,
                                                     float* __restrict__ h3seg,
                                                     const int* __restrict__ cnt,
                                                     const int* __restrict__ ord) {
  int gy = blockIdx.y;
  int s = ord[gy >> 1];
  int mat = gy & 1;
  int c = cnt[s];
  if (c == 0) return;
  int e = s >> 1;
  int tid = threadIdx.x;
  int l = tid & 63;
  int w = tid >> 6;
  int tokh = w & 1;
  int colh = w >> 1;
  int col = blockIdx.x * 128 + colh * 64 + l;
  const float* wp = (mat ? W3 : W1) + (size_t)e * HH * FF + col;
  const float* xp = xseg + (size_t)s * HH * TSEG + tokh * 8;
  float wring[16];
  float4 xa[4], xb[4];
  float acc[8];
#pragma unroll
  for (int t = 0; t < 8; ++t) acc[t] = 0.f;
#pragma unroll
  for (int k = 0; k < 16; ++k) wring[k] = wp[(size_t)k * FF];
#pragma unroll
  for (int k = 0; k < 4; ++k) {
    xa[k] = *(const float4*)(xp + (size_t)k * TSEG);
    xb[k] = *(const float4*)(xp + (size_t)k * TSEG + 4);
  }
  for (int i0 = 0; i0 < HH; i0 += 16) {
#pragma unroll
    for (int k = 0; k < 16; ++k) {
      int i = i0 + k;
      float wv = wring[k];
      int wpre = (i + 16 < HH) ? i + 16 : HH - 1;
      wring[k] = wp[(size_t)wpre * FF];
      float4 a = xa[k & 3], b = xb[k & 3];
      int xpre = (i + 4 < HH) ? i + 4 : HH - 1;
      xa[k & 3] = *(const float4*)(xp + (size_t)xpre * TSEG);
      xb[k & 3] = *(const float4*)(xp + (size_t)xpre * TSEG + 4);
      acc[0] = fmaf(a.x, wv, acc[0]);
      acc[1] = fmaf(a.y, wv, acc[1]);
      acc[2] = fmaf(a.z, wv, acc[2]);
      acc[3] = fmaf(a.w, wv, acc[3]);
      acc[4] = fmaf(b.x, wv, acc[4]);
      acc[5] = fmaf(b.y, wv, acc[5]);
      acc[6] = fmaf(b.z, wv, acc[6]);
      acc[7] = fmaf(b.w, wv, acc[7]);
    }
  }
  float* seg = (mat ? h3seg : h1seg) + ((size_t)s * FF + col) * TSEG + tokh * 8;
  *(float4*)seg = make_float4(acc[0], acc[1], acc[2], acc[3]);
  *(float4*)(seg + 4) = make_float4(acc[4], acc[5], acc[6], acc[7]);
}

// ------------------------------------------------------------- combine ----
__global__ __launch_bounds__(256) void silu_combine_kernel(float* __restrict__ h1seg,
                                                           const float* __restrict__ h3seg) {
  size_t i = (size_t)blockIdx.x * 256 + threadIdx.x;  // float4 index
  float4 h1 = ((const float4*)h1seg)[i];
  float4 h3 = ((const float4*)h3seg)[i];
  float4 r;
  r.x = (h1.x / (1.f + __expf(-h1.x))) * h3.x;
  r.y = (h1.y / (1.f + __expf(-h1.y))) * h3.y;
  r.z = (h1.z / (1.f + __expf(-h1.z))) * h3.z;
  r.w = (h1.w / (1.f + __expf(-h1.w))) * h3.w;
  ((float4*)h1seg)[i] = r;
}

// --------------------------------------------------------------- passC ----
// Wave = token-quarter over the block's 64 h-cols; lane = 1 column.
// Same dual register rings; epilogue = 4 weighted atomics per lane
// (exactly 2 contributions per out element -> deterministic fp32 sum).
__global__ __launch_bounds__(256) void passC8_kernel(const float* __restrict__ W2,
                                                     const float* __restrict__ gseg,
                                                     const int* __restrict__ cnt,
                                                     const int* __restrict__ tok,
                                                     const float* __restrict__ wts,
                                                     const int* __restrict__ ord,
                                                     float* __restrict__ out) {
  int s = ord[blockIdx.y];
  int c = cnt[s];
  if (c == 0) return;
  int e = s >> 1;
  int tid = threadIdx.x;
  int l = tid & 63;
  int tq = tid >> 6;  // token quarter
  int col = blockIdx.x * 64 + l;
  const float* wp = W2 + (size_t)e * FF * HH + col;
  const float* gp = gseg + (size_t)s * FF * TSEG + tq * 4;
  float wring[16];
  float4 xr[4];
  float acc[4];
#pragma unroll
  for (int t = 0; t < 4; ++t) acc[t] = 0.f;
#pragma unroll
  for (int k = 0; k < 16; ++k) wring[k] = wp[(size_t)k * HH];
#pragma unroll
  for (int k = 0; k < 4; ++k) xr[k] = *(const float4*)(gp + (size_t)k * TSEG);
  for (int i0 = 0; i0 < FF; i0 += 16) {
#pragma unroll
    for (int k = 0; k < 16; ++k) {
      int i = i0 + k;
      float wv = wring[k];
      int wpre = (i + 16 < FF) ? i + 16 : FF - 1;
      wring[k] = wp[(size_t)wpre * HH];
      float4 g = xr[k & 3];
      int xpre = (i + 4 < FF) ? i + 4 : FF - 1;
      xr[k & 3] = *(const float4*)(gp + (size_t)xpre * TSEG);
      acc[0] = fmaf(g.x, wv, acc[0]);
      acc[1] = fmaf(g.y, wv, acc[1]);
      acc[2] = fmaf(g.z, wv, acc[2]);
      acc[3] = fmaf(g.w, wv, acc[3]);
    }
  }
#pragma unroll
  for (int j = 0; j < 4; ++j) {
    int t = tq * 4 + j;
    if (t < c) {
      atomicAdd(out + (size_t)tok[s * TSEG + t] * HH + col,
                wts[s * TSEG + t] * acc[j]);
    }
  }
}

// -------------------------------------------------------------- launch ----
extern "C" void kernel_launch(void* const* d_in, const int* in_sizes, int n_in,
                              void* d_out, int out_size, void* d_ws, size_t ws_size,
                              hipStream_t stream) {
  const float* x  = (const float*)d_in[0];
  const float* Wg = (const float*)d_in[1];
  const float* W1 = (const float*)d_in[2];
  const float* W3 = (const float*)d_in[3];
  const float* W2 = (const float*)d_in[4];
  float* out = (float*)d_out;

  char* ws = (char*)d_ws;
  float* logits = (float*)ws;                 // 256 f32
  int*   cnt    = (int*)(ws + 1024);          // 16 i32
  int*   tok    = (int*)(ws + 1088);          // 256 i32
  float* wts    = (float*)(ws + 2112);        // 256 f32
  int*   ord    = (int*)(ws + 3136);          // 16 i32
  float* xseg   = (float*)(ws + 4096);                 // 4 MB
  float* h1seg  = xseg + (size_t)NSLOT * HH * TSEG;    // 4 MB
  float* h3seg  = h1seg + (size_t)NSLOT * FF * TSEG;   // 4 MB

  hipMemsetAsync(d_out, 0, (size_t)out_size * sizeof(float), stream);
  gate_kernel<<<BB, 256, 0, stream>>>(x, Wg, logits);
  route_kernel<<<1, 64, 0, stream>>>(logits, cnt, tok, wts, ord);
  buildx_kernel<<<dim3(HH / 256, NSLOT), 256, 0, stream>>>(x, cnt, tok, xseg);
  passB8_kernel<<<dim3(FF / 128, NSLOT * 2), 256, 0, stream>>>(W1, W3, xseg, h1seg, h3seg, cnt, ord);
  silu_combine_kernel<<<(NSLOT * FF * TSEG) / (256 * 4), 256, 0, stream>>>(h1seg, h3seg);
  passC8_kernel<<<dim3(HH / 64, NSLOT), 256, 0, stream>>>(W2, h1seg, cnt, tok, wts, ord, out);
}

// Round 9
// 448.655 us; speedup vs baseline: 2.5985x; 2.5985x over previous
//
#include <hip/hip_runtime.h>
#include <cstdint>

#define BB 32
#define HH 4096
#define FF 4096
#define EE 8
#define NSLOT 16   // 8 experts x 2 slots of <=16 tokens
#define TSEG 16
#define CH 512     // rows staged per chunk (32 KB)

// ---------------------------------------------------------------- gate ----
__global__ __launch_bounds__(256) void gate_kernel(const float* __restrict__ x,
                                                   const float* __restrict__ Wg,
                                                   float* __restrict__ logits) {
  int b = blockIdx.x;
  int tid = threadIdx.x;
  float acc[EE];
#pragma unroll
  for (int e = 0; e < EE; ++e) acc[e] = 0.f;
  const float* xb = x + (size_t)b * HH;
  for (int h = tid; h < HH; h += 256) {
    float xv = xb[h];
    const float4* wg = (const float4*)(Wg + (size_t)h * EE);
    float4 w0 = wg[0], w1 = wg[1];
    acc[0] = fmaf(xv, w0.x, acc[0]);
    acc[1] = fmaf(xv, w0.y, acc[1]);
    acc[2] = fmaf(xv, w0.z, acc[2]);
    acc[3] = fmaf(xv, w0.w, acc[3]);
    acc[4] = fmaf(xv, w1.x, acc[4]);
    acc[5] = fmaf(xv, w1.y, acc[5]);
    acc[6] = fmaf(xv, w1.z, acc[6]);
    acc[7] = fmaf(xv, w1.w, acc[7]);
  }
#pragma unroll
  for (int off = 32; off > 0; off >>= 1) {
#pragma unroll
    for (int e = 0; e < EE; ++e) acc[e] += __shfl_down(acc[e], off, 64);
  }
  __shared__ float part[4][EE];
  if ((tid & 63) == 0) {
#pragma unroll
    for (int e = 0; e < EE; ++e) part[tid >> 6][e] = acc[e];
  }
  __syncthreads();
  if (tid < EE) {
    logits[(size_t)b * EE + tid] =
        part[0][tid] + part[1][tid] + part[2][tid] + part[3][tid];
  }
}

// --------------------------------------------------------------- route ----
__global__ void route_kernel(const float* __restrict__ logits,
                             int* __restrict__ cnt,
                             int* __restrict__ tok,
                             float* __restrict__ wts,
                             int* __restrict__ ord) {
  if (threadIdx.x != 0 || blockIdx.x != 0) return;
  int e0[BB], e1[BB];
  float p0[BB], p1[BB];
  for (int b = 0; b < BB; ++b) {
    const float* L = logits + (size_t)b * EE;
    int i0 = 0;
    float v0 = L[0];
    for (int e = 1; e < EE; ++e) {
      float v = L[e];
      if (v > v0) { v0 = v; i0 = e; }
    }
    int i1 = (i0 == 0) ? 1 : 0;
    float v1 = L[i1];
    for (int e = 0; e < EE; ++e) {
      if (e == i0) continue;
      float v = L[e];
      if (v > v1) { v1 = v; i1 = e; }
    }
    float p = 1.f / (1.f + __expf(v1 - v0));
    e0[b] = i0; e1[b] = i1; p0[b] = p; p1[b] = 1.f - p;
  }
  for (int s = 0; s < NSLOT; ++s) {
    cnt[s] = 0;
    for (int t = 0; t < TSEG; ++t) { tok[s * TSEG + t] = 0; wts[s * TSEG + t] = 0.f; }
  }
  for (int e = 0; e < EE; ++e) {
    int c = 0;
    for (int b = 0; b < BB; ++b) {
      float w = 0.f;
      int sel = 0;
      if (e0[b] == e) { w = p0[b]; sel = 1; }
      else if (e1[b] == e) { w = p1[b]; sel = 1; }
      if (sel) {
        int s = e * 2 + (c >> 4);
        int t = c & 15;
        tok[s * TSEG + t] = b;
        wts[s * TSEG + t] = w;
        cnt[s] = t + 1;
        ++c;
      }
    }
  }
  int na = 0;
  for (int s = 0; s < NSLOT; ++s) if (cnt[s] > 0) ord[na++] = s;
  for (int s = 0; s < NSLOT; ++s) if (cnt[s] == 0) ord[na++] = s;
}

// -------------------------------------------------------------- buildx ----
__global__ __launch_bounds__(256) void buildx_kernel(const float* __restrict__ x,
                                                     const int* __restrict__ cnt,
                                                     const int* __restrict__ tok,
                                                     float* __restrict__ xseg) {
  int s = blockIdx.y;
  int c = cnt[s];
  if (c == 0) return;
  int tid = threadIdx.x;
  int t = tid & 15;
  int hoff = tid >> 4;
  int tk = tok[s * TSEG + t];
  bool act = t < c;
  int hbase = blockIdx.x * 256;
#pragma unroll
  for (int i = 0; i < 16; ++i) {
    int h = hbase + i * 16 + hoff;
    float v = act ? x[(size_t)tk * HH + h] : 0.f;
    xseg[((size_t)s * HH + h) * TSEG + t] = v;
  }
}

// ----------------------------------------------------------- core math ----
// Per chunk of 512 rows: x staged in LDS (lgkmcnt), weight dword/lane
// (256 B/wave, coalesced) in a depth-16 consume-oldest register ring —
// the ONLY vmcnt traffic in the hot loop. Lane owns one column for 8
// tokens (its wave's token-half): 8 FMA/row, no cross-wave reduction.
__device__ __forceinline__ void accum_chunk_lds(float* __restrict__ acc,
                                                const float* __restrict__ wp,
                                                const float* __restrict__ lx8) {
  float ring[16];
#pragma unroll
  for (int k = 0; k < 16; ++k) ring[k] = wp[(size_t)k * 4096];
  for (int i0 = 0; i0 + 16 < CH; i0 += 16) {
#pragma unroll
    for (int k = 0; k < 16; ++k) {
      float wv = ring[k];
      ring[k] = wp[(size_t)(i0 + 16 + k) * 4096];
      const float* xr = lx8 + (i0 + k) * TSEG;
      float4 a = *(const float4*)(xr);
      float4 b = *(const float4*)(xr + 4);
      acc[0] = fmaf(a.x, wv, acc[0]);
      acc[1] = fmaf(a.y, wv, acc[1]);
      acc[2] = fmaf(a.z, wv, acc[2]);
      acc[3] = fmaf(a.w, wv, acc[3]);
      acc[4] = fmaf(b.x, wv, acc[4]);
      acc[5] = fmaf(b.y, wv, acc[5]);
      acc[6] = fmaf(b.z, wv, acc[6]);
      acc[7] = fmaf(b.w, wv, acc[7]);
    }
  }
#pragma unroll
  for (int k = 0; k < 16; ++k) {
    float wv = ring[k];
    const float* xr = lx8 + (CH - 16 + k) * TSEG;
    float4 a = *(const float4*)(xr);
    float4 b = *(const float4*)(xr + 4);
    acc[0] = fmaf(a.x, wv, acc[0]);
    acc[1] = fmaf(a.y, wv, acc[1]);
    acc[2] = fmaf(a.z, wv, acc[2]);
    acc[3] = fmaf(a.w, wv, acc[3]);
    acc[4] = fmaf(b.x, wv, acc[4]);
    acc[5] = fmaf(b.y, wv, acc[5]);
    acc[6] = fmaf(b.z, wv, acc[6]);
    acc[7] = fmaf(b.w, wv, acc[7]);
  }
}

// Stage CH=512 rows x 16 floats (linear 32 KB copy, coalesced).
__device__ __forceinline__ void stage512(float* __restrict__ lx,
                                         const float* __restrict__ src, int tid) {
  const float4* s4 = (const float4*)src;
  float4* d4 = (float4*)lx;
#pragma unroll
  for (int k = 0; k < 8; ++k) d4[k * 256 + tid] = s4[k * 256 + tid];
}

// Same with fused g = silu(h1) * h3.
__device__ __forceinline__ void stage_silu512(float* __restrict__ lx,
                                              const float* __restrict__ h1p,
                                              const float* __restrict__ h3p, int tid) {
  const float4* a4 = (const float4*)h1p;
  const float4* b4 = (const float4*)h3p;
  float4* d4 = (float4*)lx;
#pragma unroll
  for (int k = 0; k < 8; ++k) {
    float4 a = a4[k * 256 + tid];
    float4 b = b4[k * 256 + tid];
    float4 g;
    g.x = (a.x / (1.f + __expf(-a.x))) * b.x;
    g.y = (a.y / (1.f + __expf(-a.y))) * b.y;
    g.z = (a.z / (1.f + __expf(-a.z))) * b.z;
    g.w = (a.w / (1.f + __expf(-a.w))) * b.w;
    d4[k * 256 + tid] = g;
  }
}

// --------------------------------------------------------------- passB ----
// Block: one matrix, 128 f-cols, all 4096 h-rows. 4 waves = (token-half,
// col-half); lane = 1 col x 8 tokens. No reduction; disjoint direct stores.
__global__ __launch_bounds__(256) void passB9_kernel(const float* __restrict__ W1,
                                                     const float* __restrict__ W3,
                                                     const float* __restrict__ xseg,
                                                     float* __restrict__ h1seg,
                                                     float* __restrict__ h3seg,
                                                     const int* __restrict__ cnt,
                                                     const int* __restrict__ ord) {
  __shared__ float lx[CH * TSEG];  // 32 KB
  int gy = blockIdx.y;
  int s = ord[gy >> 1];
  int mat = gy & 1;
  int c = cnt[s];
  if (c == 0) return;
  int e = s >> 1;
  int tid = threadIdx.x;
  int l = tid & 63;
  int w = tid >> 6;
  int tokh = w & 1;
  int colh = w >> 1;
  int col = blockIdx.x * 128 + colh * 64 + l;
  const float* wp = (mat ? W3 : W1) + (size_t)e * HH * FF + col;
  const float* xsrc = xseg + (size_t)s * HH * TSEG;
  float acc[8];
#pragma unroll
  for (int t = 0; t < 8; ++t) acc[t] = 0.f;
  for (int ch = 0; ch < HH / CH; ++ch) {
    __syncthreads();
    stage512(lx, xsrc + (size_t)(ch * CH) * TSEG, tid);
    __syncthreads();
    accum_chunk_lds(acc, wp + (size_t)(ch * CH) * FF, lx + tokh * 8);
  }
  float* seg = (mat ? h3seg : h1seg) + ((size_t)s * FF + col) * TSEG + tokh * 8;
  *(float4*)seg = make_float4(acc[0], acc[1], acc[2], acc[3]);
  *(float4*)(seg + 4) = make_float4(acc[4], acc[5], acc[6], acc[7]);
}

// --------------------------------------------------------------- passC ----
// Block: 128 h-cols, rows [z*2048,+2048) of W2 (4 chunks); silu fused in
// staging; lane = 1 col x 8 tokens; weighted atomics (<=4 adds/element).
__global__ __launch_bounds__(256) void passC9_kernel(const float* __restrict__ W2,
                                                     const float* __restrict__ h1seg,
                                                     const float* __restrict__ h3seg,
                                                     const int* __restrict__ cnt,
                                                     const int* __restrict__ tok,
                                                     const float* __restrict__ wts,
                                                     const int* __restrict__ ord,
                                                     float* __restrict__ out) {
  __shared__ float lx[CH * TSEG];  // 32 KB
  __shared__ int stok[TSEG];
  __shared__ float swt[TSEG];
  int gy = blockIdx.y;
  int s = ord[gy >> 1];
  int z = gy & 1;
  int c = cnt[s];
  if (c == 0) return;
  int e = s >> 1;
  int tid = threadIdx.x;
  int l = tid & 63;
  int w = tid >> 6;
  int tokh = w & 1;
  int colh = w >> 1;
  int col = blockIdx.x * 128 + colh * 64 + l;
  if (tid < TSEG) {
    stok[tid] = tok[s * TSEG + tid];
    swt[tid] = wts[s * TSEG + tid];
  }
  const float* wp = W2 + (size_t)e * FF * HH + (size_t)(z * 2048) * HH + col;
  const float* h1src = h1seg + ((size_t)s * FF + z * 2048) * TSEG;
  const float* h3src = h3seg + ((size_t)s * FF + z * 2048) * TSEG;
  float acc[8];
#pragma unroll
  for (int t = 0; t < 8; ++t) acc[t] = 0.f;
  for (int ch = 0; ch < 2048 / CH; ++ch) {
    __syncthreads();
    stage_silu512(lx, h1src + (size_t)(ch * CH) * TSEG,
                  h3src + (size_t)(ch * CH) * TSEG, tid);
    __syncthreads();
    accum_chunk_lds(acc, wp + (size_t)(ch * CH) * HH, lx + tokh * 8);
  }
  float* op = out + col;
#pragma unroll
  for (int j = 0; j < 8; ++j) {
    int t = tokh * 8 + j;
    if (t < c) atomicAdd(op + (size_t)stok[t] * HH, swt[t] * acc[j]);
  }
}

// -------------------------------------------------------------- launch ----
extern "C" void kernel_launch(void* const* d_in, const int* in_sizes, int n_in,
                              void* d_out, int out_size, void* d_ws, size_t ws_size,
                              hipStream_t stream) {
  const float* x  = (const float*)d_in[0];
  const float* Wg = (const float*)d_in[1];
  const float* W1 = (const float*)d_in[2];
  const float* W3 = (const float*)d_in[3];
  const float* W2 = (const float*)d_in[4];
  float* out = (float*)d_out;

  char* ws = (char*)d_ws;
  float* logits = (float*)ws;                 // 256 f32
  int*   cnt    = (int*)(ws + 1024);          // 16 i32
  int*   tok    = (int*)(ws + 1088);          // 256 i32
  float* wts    = (float*)(ws + 2112);        // 256 f32
  int*   ord    = (int*)(ws + 3136);          // 16 i32
  float* xseg   = (float*)(ws + 4096);                 // 4 MB
  float* h1seg  = xseg + (size_t)NSLOT * HH * TSEG;    // 4 MB
  float* h3seg  = h1seg + (size_t)NSLOT * FF * TSEG;   // 4 MB

  hipMemsetAsync(d_out, 0, (size_t)out_size * sizeof(float), stream);
  gate_kernel<<<BB, 256, 0, stream>>>(x, Wg, logits);
  route_kernel<<<1, 64, 0, stream>>>(logits, cnt, tok, wts, ord);
  buildx_kernel<<<dim3(HH / 256, NSLOT), 256, 0, stream>>>(x, cnt, tok, xseg);
  passB9_kernel<<<dim3(FF / 128, NSLOT * 2), 256, 0, stream>>>(W1, W3, xseg, h1seg, h3seg, cnt, ord);
  passC9_kernel<<<dim3(HH / 128, NSLOT * 2), 256, 0, stream>>>(W2, h1seg, h3seg, cnt, tok, wts, ord, out);
}

// Round 10
// 371.745 us; speedup vs baseline: 3.1361x; 1.2069x over previous
//
#include <hip/hip_runtime.h>
#include <cstdint>

#define BB 32
#define HH 4096
#define FF 4096
#define EE 8
#define NSLOT 16   // 8 experts x 2 slots of <=16 tokens
#define TSEG 16
#define CH 256       // rows per staged chunk (16 KB buffer)
#define SCR_STR 36   // reduce scratch stride (floats)

// ---------------------------------------------------------------- gate ----
__global__ __launch_bounds__(256) void gate_kernel(const float* __restrict__ x,
                                                   const float* __restrict__ Wg,
                                                   float* __restrict__ logits) {
  int b = blockIdx.x;
  int tid = threadIdx.x;
  float acc[EE];
#pragma unroll
  for (int e = 0; e < EE; ++e) acc[e] = 0.f;
  const float* xb = x + (size_t)b * HH;
  for (int h = tid; h < HH; h += 256) {
    float xv = xb[h];
    const float4* wg = (const float4*)(Wg + (size_t)h * EE);
    float4 w0 = wg[0], w1 = wg[1];
    acc[0] = fmaf(xv, w0.x, acc[0]);
    acc[1] = fmaf(xv, w0.y, acc[1]);
    acc[2] = fmaf(xv, w0.z, acc[2]);
    acc[3] = fmaf(xv, w0.w, acc[3]);
    acc[4] = fmaf(xv, w1.x, acc[4]);
    acc[5] = fmaf(xv, w1.y, acc[5]);
    acc[6] = fmaf(xv, w1.z, acc[6]);
    acc[7] = fmaf(xv, w1.w, acc[7]);
  }
#pragma unroll
  for (int off = 32; off > 0; off >>= 1) {
#pragma unroll
    for (int e = 0; e < EE; ++e) acc[e] += __shfl_down(acc[e], off, 64);
  }
  __shared__ float part[4][EE];
  if ((tid & 63) == 0) {
#pragma unroll
    for (int e = 0; e < EE; ++e) part[tid >> 6][e] = acc[e];
  }
  __syncthreads();
  if (tid < EE) {
    logits[(size_t)b * EE + tid] =
        part[0][tid] + part[1][tid] + part[2][tid] + part[3][tid];
  }
}

// --------------------------------------------------------------- route ----
__global__ void route_kernel(const float* __restrict__ logits,
                             int* __restrict__ cnt,
                             int* __restrict__ tok,
                             float* __restrict__ wts,
                             int* __restrict__ ord) {
  if (threadIdx.x != 0 || blockIdx.x != 0) return;
  int e0[BB], e1[BB];
  float p0[BB], p1[BB];
  for (int b = 0; b < BB; ++b) {
    const float* L = logits + (size_t)b * EE;
    int i0 = 0;
    float v0 = L[0];
    for (int e = 1; e < EE; ++e) {
      float v = L[e];
      if (v > v0) { v0 = v; i0 = e; }
    }
    int i1 = (i0 == 0) ? 1 : 0;
    float v1 = L[i1];
    for (int e = 0; e < EE; ++e) {
      if (e == i0) continue;
      float v = L[e];
      if (v > v1) { v1 = v; i1 = e; }
    }
    float p = 1.f / (1.f + __expf(v1 - v0));
    e0[b] = i0; e1[b] = i1; p0[b] = p; p1[b] = 1.f - p;
  }
  for (int s = 0; s < NSLOT; ++s) {
    cnt[s] = 0;
    for (int t = 0; t < TSEG; ++t) { tok[s * TSEG + t] = 0; wts[s * TSEG + t] = 0.f; }
  }
  for (int e = 0; e < EE; ++e) {
    int c = 0;
    for (int b = 0; b < BB; ++b) {
      float w = 0.f;
      int sel = 0;
      if (e0[b] == e) { w = p0[b]; sel = 1; }
      else if (e1[b] == e) { w = p1[b]; sel = 1; }
      if (sel) {
        int s = e * 2 + (c >> 4);
        int t = c & 15;
        tok[s * TSEG + t] = b;
        wts[s * TSEG + t] = w;
        cnt[s] = t + 1;
        ++c;
      }
    }
  }
  int na = 0;
  for (int s = 0; s < NSLOT; ++s) if (cnt[s] > 0) ord[na++] = s;
  for (int s = 0; s < NSLOT; ++s) if (cnt[s] == 0) ord[na++] = s;
}

// -------------------------------------------------------------- buildx ----
__global__ __launch_bounds__(256) void buildx_kernel(const float* __restrict__ x,
                                                     const int* __restrict__ cnt,
                                                     const int* __restrict__ tok,
                                                     float* __restrict__ xseg) {
  int s = blockIdx.y;
  int c = cnt[s];
  if (c == 0) return;
  int tid = threadIdx.x;
  int t = tid & 15;
  int hoff = tid >> 4;
  int tk = tok[s * TSEG + t];
  bool act = t < c;
  int hbase = blockIdx.x * 256;
#pragma unroll
  for (int i = 0; i < 16; ++i) {
    int h = hbase + i * 16 + hoff;
    float v = act ? x[(size_t)tk * HH + h] : 0.f;
    xseg[((size_t)s * HH + h) * TSEG + t] = v;
  }
}

// ----------------------------------------------------------- core math ----
// Async stage of one CH=256-row chunk (16 KB) via global_load_lds width-16:
// 4 instructions/thread, LDS dest is wave-uniform base + lane*16 (linear).
__device__ __forceinline__ void stage_async(float* __restrict__ lbuf,
                                            const float* __restrict__ src, int tid) {
#pragma unroll
  for (int k = 0; k < 4; ++k) {
    int q = k * 256 + tid;  // float4 index
    __builtin_amdgcn_global_load_lds(
        (const __attribute__((address_space(1))) unsigned int*)(src + (size_t)q * 4),
        (__attribute__((address_space(3))) unsigned int*)(lbuf + (size_t)q * 4),
        16, 0, 0);
  }
}

// acc layout: acc[0..7]=col+0 (8 toks), acc[8..15]=col+1, acc[16..23]=col+2,
// acc[24..31]=col+3.
__device__ __forceinline__ void fma32(float* __restrict__ acc,
                                      const float* __restrict__ xr, float4 wv) {
  float4 a = *(const float4*)xr;
  float4 b = *(const float4*)(xr + 4);
  float xs[8] = {a.x, a.y, a.z, a.w, b.x, b.y, b.z, b.w};
#pragma unroll
  for (int t = 0; t < 8; ++t) {
    acc[t]      = fmaf(xs[t], wv.x, acc[t]);
    acc[8 + t]  = fmaf(xs[t], wv.y, acc[8 + t]);
    acc[16 + t] = fmaf(xs[t], wv.z, acc[16 + t]);
    acc[24 + t] = fmaf(xs[t], wv.w, acc[24 + t]);
  }
}

// 64 rows, depth-8 float4 weight ring (the only NEW vmcnt traffic; pending
// stage loads are older in the queue so waiting on the ring never adds
// stalls for them). x via LDS broadcast (lgkmcnt).
__device__ __forceinline__ void accum64(float* __restrict__ acc,
                                        const float4* __restrict__ wp4,
                                        const float* __restrict__ lx8) {
  float4 ring[8];
#pragma unroll
  for (int k = 0; k < 8; ++k) ring[k] = wp4[(size_t)k * 1024];
  for (int i0 = 0; i0 + 8 < 64; i0 += 8) {
#pragma unroll
    for (int k = 0; k < 8; ++k) {
      float4 wv = ring[k];
      ring[k] = wp4[(size_t)(i0 + 8 + k) * 1024];
      fma32(acc, lx8 + (i0 + k) * TSEG, wv);
    }
  }
#pragma unroll
  for (int k = 0; k < 8; ++k)
    fma32(acc, lx8 + (56 + k) * TSEG, ring[k]);
}

// --------------------------------------------------------------- passB ----
// Block: one matrix, 128 f-cols, all 4096 h-rows. Lane = 4 cols x token-half;
// 4 waves = row-quarters of each chunk. Double-buffered async staging, one
// barrier per chunk. Epilogue: LDS reduce + plain stores.
__global__ __launch_bounds__(256) void passB10_kernel(const float* __restrict__ W1,
                                                      const float* __restrict__ W3,
                                                      const float* __restrict__ xseg,
                                                      float* __restrict__ h1seg,
                                                      float* __restrict__ h3seg,
                                                      const int* __restrict__ cnt,
                                                      const int* __restrict__ ord) {
  __shared__ float lds[9216];  // 36 KB: 2 x 4096 buffers; reduce scratch reuses all
  int gy = blockIdx.y;
  int s = ord[gy >> 1];
  int mat = gy & 1;
  int c = cnt[s];
  if (c == 0) return;
  int e = s >> 1;
  int tid = threadIdx.x;
  int l = tid & 63;
  int w = tid >> 6;
  int colbase = blockIdx.x * 128;
  const float* Wm = (mat ? W3 : W1) + (size_t)e * HH * FF + colbase + (l & 31) * 4;
  const float* xsrc = xseg + (size_t)s * HH * TSEG;
  int half8 = (l >> 5) * 8;
  float acc[32];
#pragma unroll
  for (int t = 0; t < 32; ++t) acc[t] = 0.f;
  stage_async(lds, xsrc, tid);
  __syncthreads();
  for (int ch = 0; ch < HH / CH; ++ch) {
    if (ch + 1 < HH / CH)
      stage_async(lds + ((ch + 1) & 1) * (CH * TSEG),
                  xsrc + (size_t)(ch + 1) * CH * TSEG, tid);
    const float4* wp4 = (const float4*)(Wm + (size_t)(ch * CH + w * 64) * FF);
    accum64(acc, wp4, lds + (ch & 1) * (CH * TSEG) + (w * 64) * TSEG + half8);
    __syncthreads();  // drains this wave's stage loads; publishes next buffer
  }
  float* rp = lds + (size_t)(w * 64 + l) * SCR_STR;
#pragma unroll
  for (int q = 0; q < 32; q += 4) *(float4*)(rp + q) = *(const float4*)&acc[q];
  __syncthreads();
  int col_off = tid & 127;
  int half = tid >> 7;
  int baselane = (col_off >> 2) | (half << 5);
  int fbase = (col_off & 3) * 8;
  float v[8];
#pragma unroll
  for (int j = 0; j < 8; ++j) {
    float sum = 0.f;
#pragma unroll
    for (int w4 = 0; w4 < 4; ++w4)
      sum += lds[(w4 * 64 + baselane) * SCR_STR + fbase + j];
    v[j] = sum;
  }
  float* seg = (mat ? h3seg : h1seg) +
               ((size_t)s * FF + colbase + col_off) * TSEG + half * 8;
  *(float4*)seg = *(const float4*)&v[0];
  *(float4*)(seg + 4) = *(const float4*)&v[4];
}

// ------------------------------------------------------------- combine ----
// In-place: h1seg = silu(h1seg) * h3seg (only active slots).
__global__ __launch_bounds__(256) void silu_combine_kernel(float* __restrict__ h1seg,
                                                           const float* __restrict__ h3seg,
                                                           const int* __restrict__ cnt) {
  int s = blockIdx.y;
  if (cnt[s] == 0) return;
  size_t i = (size_t)s * (FF * TSEG / 4) + (size_t)blockIdx.x * 256 + threadIdx.x;
  float4 h1 = ((const float4*)h1seg)[i];
  float4 h3 = ((const float4*)h3seg)[i];
  float4 r;
  r.x = (h1.x / (1.f + __expf(-h1.x))) * h3.x;
  r.y = (h1.y / (1.f + __expf(-h1.y))) * h3.y;
  r.z = (h1.z / (1.f + __expf(-h1.z))) * h3.z;
  r.w = (h1.w / (1.f + __expf(-h1.w))) * h3.w;
  ((float4*)h1seg)[i] = r;
}

// --------------------------------------------------------------- passC ----
// Block: 128 h-cols, rows [z*2048,+2048) of W2 (8 chunks). Same layout;
// epilogue reduce + weighted atomics into out (<=4 adds/element).
__global__ __launch_bounds__(256) void passC10_kernel(const float* __restrict__ W2,
                                                      const float* __restrict__ gseg,
                                                      const int* __restrict__ cnt,
                                                      const int* __restrict__ tok,
                                                      const float* __restrict__ wts,
                                                      const int* __restrict__ ord,
                                                      float* __restrict__ out) {
  __shared__ float lds[9216];
  __shared__ int stok[TSEG];
  __shared__ float swt[TSEG];
  int gy = blockIdx.y;
  int s = ord[gy >> 1];
  int z = gy & 1;
  int c = cnt[s];
  if (c == 0) return;
  int e = s >> 1;
  int tid = threadIdx.x;
  int l = tid & 63;
  int w = tid >> 6;
  int colbase = blockIdx.x * 128;
  if (tid < TSEG) {
    stok[tid] = tok[s * TSEG + tid];
    swt[tid] = wts[s * TSEG + tid];
  }
  const float* Wm = W2 + (size_t)e * FF * HH + (size_t)(z * 2048) * HH +
                    colbase + (l & 31) * 4;
  const float* gsrc = gseg + ((size_t)s * FF + z * 2048) * TSEG;
  int half8 = (l >> 5) * 8;
  float acc[32];
#pragma unroll
  for (int t = 0; t < 32; ++t) acc[t] = 0.f;
  stage_async(lds, gsrc, tid);
  __syncthreads();
  for (int ch = 0; ch < 2048 / CH; ++ch) {
    if (ch + 1 < 2048 / CH)
      stage_async(lds + ((ch + 1) & 1) * (CH * TSEG),
                  gsrc + (size_t)(ch + 1) * CH * TSEG, tid);
    const float4* wp4 = (const float4*)(Wm + (size_t)(ch * CH + w * 64) * HH);
    accum64(acc, wp4, lds + (ch & 1) * (CH * TSEG) + (w * 64) * TSEG + half8);
    __syncthreads();
  }
  float* rp = lds + (size_t)(w * 64 + l) * SCR_STR;
#pragma unroll
  for (int q = 0; q < 32; q += 4) *(float4*)(rp + q) = *(const float4*)&acc[q];
  __syncthreads();
  int col_off = tid & 127;
  int half = tid >> 7;
  int baselane = (col_off >> 2) | (half << 5);
  int fbase = (col_off & 3) * 8;
  float* op = out + colbase + col_off;
#pragma unroll
  for (int j = 0; j < 8; ++j) {
    int t = half * 8 + j;
    if (t < c) {
      float sum = 0.f;
#pragma unroll
      for (int w4 = 0; w4 < 4; ++w4)
        sum += lds[(w4 * 64 + baselane) * SCR_STR + fbase + j];
      atomicAdd(op + (size_t)stok[t] * HH, swt[t] * sum);
    }
  }
}

// -------------------------------------------------------------- launch ----
extern "C" void kernel_launch(void* const* d_in, const int* in_sizes, int n_in,
                              void* d_out, int out_size, void* d_ws, size_t ws_size,
                              hipStream_t stream) {
  const float* x  = (const float*)d_in[0];
  const float* Wg = (const float*)d_in[1];
  const float* W1 = (const float*)d_in[2];
  const float* W3 = (const float*)d_in[3];
  const float* W2 = (const float*)d_in[4];
  float* out = (float*)d_out;

  char* ws = (char*)d_ws;
  float* logits = (float*)ws;                 // 256 f32
  int*   cnt    = (int*)(ws + 1024);          // 16 i32
  int*   tok    = (int*)(ws + 1088);          // 256 i32
  float* wts    = (float*)(ws + 2112);        // 256 f32
  int*   ord    = (int*)(ws + 3136);          // 16 i32
  float* xseg   = (float*)(ws + 4096);                 // 4 MB
  float* h1seg  = xseg + (size_t)NSLOT * HH * TSEG;    // 4 MB
  float* h3seg  = h1seg + (size_t)NSLOT * FF * TSEG;   // 4 MB

  hipMemsetAsync(d_out, 0, (size_t)out_size * sizeof(float), stream);
  gate_kernel<<<BB, 256, 0, stream>>>(x, Wg, logits);
  route_kernel<<<1, 64, 0, stream>>>(logits, cnt, tok, wts, ord);
  buildx_kernel<<<dim3(HH / 256, NSLOT), 256, 0, stream>>>(x, cnt, tok, xseg);
  passB10_kernel<<<dim3(FF / 128, NSLOT * 2), 256, 0, stream>>>(W1, W3, xseg, h1seg, h3seg, cnt, ord);
  silu_combine_kernel<<<dim3(FF * TSEG / 1024, NSLOT), 256, 0, stream>>>(h1seg, h3seg, cnt);
  passC10_kernel<<<dim3(HH / 128, NSLOT * 2), 256, 0, stream>>>(W2, h1seg, cnt, tok, wts, ord, out);
}